// Round 9
// baseline (774.203 us; speedup 1.0000x reference)
//
#include <hip/hip_runtime.h>
#include <math.h>

using u16 = unsigned short;
using u32 = unsigned int;

typedef __attribute__((ext_vector_type(8))) short short8;   // 8 x bf16 (4 VGPRs)
typedef __attribute__((ext_vector_type(4))) float float4v;  // MFMA C/D

#define S_LEN 4032   // 9*16*28
#define DIM   1536
#define NH    12
#define HD    128
#define F_DIM 9
#define H_DIM 16
#define W_DIM 28
#define KSPLIT_AT 2048   // 32 tiles / 31 tiles
#define NX4 1548288      // S_LEN*DIM/4
#define NW4 589824       // DIM*DIM/4

__device__ __forceinline__ float b2f(u16 v) {
  return __uint_as_float(((u32)v) << 16);
}
__device__ __forceinline__ u16 f2bf(float f) {
  u32 u = __float_as_uint(f);
  u32 r = (u + 0x7FFFu + ((u >> 16) & 1u)) >> 16;  // RNE
  return (u16)r;
}
// pack two floats -> two bf16 by truncation (3 VALU ops; P in [0, 2^-3.6] so
// trunc error <= 2^-8 relative -- inside the absmax budget)
__device__ __forceinline__ u32 pack_trunc(float lo, float hi) {
  return (__float_as_uint(lo) >> 16) | (__float_as_uint(hi) & 0xFFFF0000u);
}

// async global->LDS, 16B per lane; LDS dst must be wave-uniform base + lane*16
__device__ __forceinline__ void gld16(const void* g, void* l) {
  __builtin_amdgcn_global_load_lds(
      (const __attribute__((address_space(1))) void*)g,
      (__attribute__((address_space(3))) void*)l, 16, 0, 0);
}

// ---------------------------------------------------------------------------
// Fused f32->bf16 cast of x, Wq, Wk, Wv, Wo (single launch).
// ---------------------------------------------------------------------------
__global__ void __launch_bounds__(256) cast_all(
    const float* __restrict__ x, const float* __restrict__ wq,
    const float* __restrict__ wk, const float* __restrict__ wv,
    const float* __restrict__ wo,
    u16* __restrict__ xb, u16* __restrict__ wqb,
    u16* __restrict__ wkb, u16* __restrict__ wvb, u16* __restrict__ wob)
{
  int i = blockIdx.x * 256 + threadIdx.x;
  const float* s; u16* d; int j;
  if (i < NX4)                { s = x;  d = xb;  j = i; }
  else if (i < NX4 + NW4)     { s = wq; d = wqb; j = i - NX4; }
  else if (i < NX4 + 2*NW4)   { s = wk; d = wkb; j = i - NX4 - NW4; }
  else if (i < NX4 + 3*NW4)   { s = wv; d = wvb; j = i - NX4 - 2*NW4; }
  else                        { s = wo; d = wob; j = i - NX4 - 3*NW4; }
  const float4 v = ((const float4*)s)[j];
  ushort4 o;
  o.x = f2bf(v.x); o.y = f2bf(v.y); o.z = f2bf(v.z); o.w = f2bf(v.w);
  ((ushort4*)d)[j] = o;
}

// ---------------------------------------------------------------------------
// GEMM: Out[m,n] = sum_k A[m,k] * W[n,k] + bias[n]   (bf16 in, bf16/f32 out)
// 128x128 tile / block, 4 waves (2x2 of 64x64), BK=64, 16x16x32 bf16 MFMA.
// ---------------------------------------------------------------------------
template <bool F32OUT>
__device__ __forceinline__ void gemm_core(
    const u16* __restrict__ A, const u16* __restrict__ Bw,
    const float* __restrict__ bias, void* __restrict__ OutV,
    int bm, int bn)
{
  __shared__ u16 As[128 * 64];
  __shared__ u16 Bs[128 * 64];
  const int tid  = threadIdx.x;
  const int wave = tid >> 6, lane = tid & 63;
  const int quad = lane >> 4, l15 = lane & 15;
  const int wm = wave >> 1, wn = wave & 1;

  float4v acc[4][4] = {};

  const int arow = lane >> 3;        // 0..7 row within 8-row segment
  const int acol = (lane & 7) * 8;   // element offset in K

  for (int kt = 0; kt < DIM; kt += 64) {
#pragma unroll
    for (int c = 0; c < 4; ++c) {
      int seg = wave * 4 + c;        // 16 segments of 8 rows x 128B
      int row = seg * 8 + arow;
      int ga = bm + row; if (ga > S_LEN - 1) ga = S_LEN - 1;  // clamp tail rows
      gld16(&A[(size_t)ga * DIM + kt + acol], &As[seg * 512]);
      gld16(&Bw[(size_t)(bn + row) * DIM + kt + acol], &Bs[seg * 512]);
    }
    __syncthreads();
#pragma unroll
    for (int ks = 0; ks < 64; ks += 32) {
      short8 af[4], bf[4];
#pragma unroll
      for (int mt = 0; mt < 4; ++mt)
        af[mt] = *(const short8*)&As[(wm * 64 + mt * 16 + l15) * 64 + ks + quad * 8];
#pragma unroll
      for (int nt = 0; nt < 4; ++nt)
        bf[nt] = *(const short8*)&Bs[(wn * 64 + nt * 16 + l15) * 64 + ks + quad * 8];
#pragma unroll
      for (int mt = 0; mt < 4; ++mt)
#pragma unroll
        for (int nt = 0; nt < 4; ++nt)
          acc[mt][nt] = __builtin_amdgcn_mfma_f32_16x16x32_bf16(af[mt], bf[nt], acc[mt][nt], 0, 0, 0);
    }
    __syncthreads();
  }

  // epilogue: C row = quad*4+r, col = lane&15
#pragma unroll
  for (int mt = 0; mt < 4; ++mt) {
    const int row = bm + wm * 64 + mt * 16 + quad * 4;
#pragma unroll
    for (int nt = 0; nt < 4; ++nt) {
      const int col = bn + wn * 64 + nt * 16 + l15;
      const float bv = bias[col];
#pragma unroll
      for (int r = 0; r < 4; ++r) {
        float v = acc[mt][nt][r] + bv;
        if (row + r < S_LEN) {
          if (F32OUT) ((float*)OutV)[(size_t)(row + r) * DIM + col] = v;
          else        ((u16*)OutV)[(size_t)(row + r) * DIM + col] = f2bf(v);
        }
      }
    }
  }
}

__global__ void __launch_bounds__(256) gemm_qkv(
    const u16* __restrict__ X,
    const u16* __restrict__ Wq, const u16* __restrict__ Wk, const u16* __restrict__ Wv,
    const float* __restrict__ bq, const float* __restrict__ bk, const float* __restrict__ bv,
    u16* __restrict__ Qb, u16* __restrict__ Kb, u16* __restrict__ Vb)
{
  const int z = blockIdx.z;
  const u16* B    = (z == 0) ? Wq : (z == 1) ? Wk : Wv;
  const float* bi = (z == 0) ? bq : (z == 1) ? bk : bv;
  u16* O          = (z == 0) ? Qb : (z == 1) ? Kb : Vb;
  gemm_core<false>(X, B, bi, O, blockIdx.y * 128, blockIdx.x * 128);
}

__global__ void __launch_bounds__(256) gemm_wo(
    const u16* __restrict__ A, const u16* __restrict__ Wo,
    const float* __restrict__ bo, float* __restrict__ Out)
{
  gemm_core<true>(A, Wo, bo, Out, blockIdx.y * 128, blockIdx.x * 128);
}

// ---------------------------------------------------------------------------
// RMS (sumsq computed in-block over full 1536) + 3-axis RoPE, in place on Q,K.
// ---------------------------------------------------------------------------
__global__ void __launch_bounds__(256) rms_rope(
    u16* Q, u16* K,
    const float* __restrict__ gq, const float* __restrict__ gk,
    const float* __restrict__ cf, const float* __restrict__ sf,
    const float* __restrict__ ch, const float* __restrict__ sh,
    const float* __restrict__ cw, const float* __restrict__ sw)
{
  __shared__ float red[2][4];
  const int s = blockIdx.x;
  const int t = threadIdx.x;
  const int wave = t >> 6, lane = t & 63;
  const size_t rowb = (size_t)s * DIM + t * 6;

  u16 qv[6], kv[6];
#pragma unroll
  for (int j = 0; j < 6; ++j) { qv[j] = Q[rowb + j]; kv[j] = K[rowb + j]; }

  float sq = 0.f, sk = 0.f;
#pragma unroll
  for (int j = 0; j < 6; ++j) {
    float a = b2f(qv[j]); sq += a * a;
    float b = b2f(kv[j]); sk += b * b;
  }
#pragma unroll
  for (int m = 1; m < 64; m <<= 1) {
    sq += __shfl_xor(sq, m, 64);
    sk += __shfl_xor(sk, m, 64);
  }
  if (lane == 0) { red[0][wave] = sq; red[1][wave] = sk; }
  __syncthreads();
  const float tq = red[0][0] + red[0][1] + red[0][2] + red[0][3];
  const float tk = red[1][0] + red[1][1] + red[1][2] + red[1][3];
  const float scq = rsqrtf(tq * (1.0f / DIM) + 1e-6f);
  const float sck = rsqrtf(tk * (1.0f / DIM) + 1e-6f);

  const int f  = s / (H_DIM * W_DIM);
  const int hh = (s / W_DIM) % H_DIM;
  const int w  = s % W_DIM;

#pragma unroll
  for (int j = 0; j < 3; ++j) {
    const int pi = t * 3 + j;       // global pair index 0..767
    const int c = pi & 63;          // rotary pair within head (C=64)
    float co, si;
    if (c < 22)      { co = cf[f * 22 + c];        si = sf[f * 22 + c]; }
    else if (c < 43) { co = ch[hh * 21 + c - 22];  si = sh[hh * 21 + c - 22]; }
    else             { co = cw[w * 21 + c - 43];   si = sw[w * 21 + c - 43]; }
    const int gi = 2 * pi;          // == head*128 + 2*c
    const size_t base = (size_t)s * DIM + gi;
    {
      float e = b2f(qv[2 * j])     * scq * gq[gi];
      float o = b2f(qv[2 * j + 1]) * scq * gq[gi + 1];
      Q[base]     = f2bf(e * co - o * si);
      Q[base + 1] = f2bf(e * si + o * co);
    }
    {
      float e = b2f(kv[2 * j])     * sck * gk[gi];
      float o = b2f(kv[2 * j + 1]) * sck * gk[gi + 1];
      K[base]     = f2bf(e * co - o * si);
      K[base + 1] = f2bf(e * si + o * co);
    }
  }
}

// ---------------------------------------------------------------------------
// V transpose: Vt[d][s] = V[s][d]  (bf16), 64x64 LDS tiles.
// ---------------------------------------------------------------------------
__global__ void __launch_bounds__(256) transpose_v(
    const u16* __restrict__ V, u16* __restrict__ Vt)
{
  __shared__ u16 tile[64][65];
  const int s0 = blockIdx.x * 64, d0 = blockIdx.y * 64;
  const int t = threadIdx.x;
#pragma unroll
  for (int i = 0; i < 16; ++i) {
    int idx = t + i * 256; int rr = idx >> 6, cc = idx & 63;
    tile[rr][cc] = V[(size_t)(s0 + rr) * DIM + d0 + cc];
  }
  __syncthreads();
#pragma unroll
  for (int i = 0; i < 16; ++i) {
    int idx = t + i * 256; int rr = idx >> 6, cc = idx & 63;
    Vt[(size_t)(d0 + rr) * S_LEN + s0 + cc] = tile[cc][rr];
  }
}

// ---------------------------------------------------------------------------
// Flash attention v7: LDS diet -> 4 blocks/CU.
// Ks 16KB + Vs 16KB + Ps 8KB = exactly 40960B => 4 blocks/CU (16 waves).
// Ps is one per-wave 16x64 tile (stride 64, XOR-swizzled 16B chunks:
// chunk ^= l15&7) processed sequentially for mt=0,1 with explicit
// s_waitcnt lgkmcnt(0) between write->read->next-write phases.
// Everything else per r8: static-max softmax (M0=20; RMS-normalized q,k
// bound |s*log2e/sqrt(128)| <= 16.4), transposed scores, ksplit, XCD
// pinning, gld16 staging, phase-split overlap.
// ---------------------------------------------------------------------------
__global__ void __launch_bounds__(256, 4) attn_kernel(
    const u16* __restrict__ rq, const u16* __restrict__ rk,
    const u16* __restrict__ vt,
    u16* __restrict__ po, float* __restrict__ pl)
{
  __shared__ u16 Ks[64 * 128];      // 16 KB [key][d]; slot(kr,kc) holds chunk kc^(kr&15)
  __shared__ u16 Vs[128 * 64];      // 16 KB [d][key]; slot(vd,vc) holds chunk vc^(vd&7)
  __shared__ u16 Ps[4][16 * 64];    //  8 KB per-wave [query16][key64], XOR-swizzled

  // swizzled decode: slice pinned to XCD = id&7 (round-robin dispatch)
  const int id    = blockIdx.x;
  const int xcd   = id & 7;
  const int band  = id >> 8;          // 0..2
  const int slot  = (id >> 3) & 31;   // q-block 0..31
  const int slice = band * 8 + xcd;   // 0..23
  const int h     = slice % NH;
  const int split = slice / NH;
  const int k_begin = split == 0 ? 0 : KSPLIT_AT;
  const int k_end   = split == 0 ? KSPLIT_AT : S_LEN;
  const int qb = slot * 128;
  const int tid = threadIdx.x, wave = tid >> 6, lane = tid & 63;
  const int quad = lane >> 4, l15 = lane & 15;
  const int q0 = qb + wave * 32;

  const int kr_l   = (lane >> 4);          // K row within 4-row seg
  const int kc_l   = lane & 15;
  const int vdr_l  = (lane >> 3);          // V d-row within 8-row seg
  const int vc_l   = lane & 7;

  // Q fragments (B-operand: n=query=l15, k=d=quad*8+j)
  short8 qf[2][4];
#pragma unroll
  for (int mt = 0; mt < 2; ++mt) {
    int row = q0 + mt * 16 + l15; if (row > S_LEN - 1) row = S_LEN - 1;
#pragma unroll
    for (int c = 0; c < 4; ++c)
      qf[mt][c] = *(const short8*)&rq[(size_t)row * DIM + h * HD + c * 32 + quad * 8];
  }

  float4v o[2][8] = {};                 // O^T: row=d(quad*4+r), col=query(l15)
  float l_[2] = {0.f, 0.f};

  const float SC = 0.08838834764831845f * 1.4426950408889634f;  // rsqrt(128)*log2(e)
  const float M0 = 20.0f;  // static max (log2 domain); hard bound is 16.4

  // ---- prologue: stage K(k_begin) ----
#pragma unroll
  for (int c = 0; c < 4; ++c) {
    const int seg = wave * 4 + c;
    const int kr = seg * 4 + kr_l;
    gld16(&rk[(size_t)(k_begin + kr) * DIM + h * HD + ((kc_l ^ (kr & 15)) << 3)],
          &Ks[seg * 512]);
  }
  __syncthreads();   // drain K(0)

  for (int kt = k_begin; kt < k_end; kt += 64) {
    // ---- issue V(kt): overlapped with QK + softmax below ----
#pragma unroll
    for (int c = 0; c < 4; ++c) {
      const int seg = wave * 4 + c;
      const int vd = seg * 8 + vdr_l;
      gld16(&vt[(size_t)(h * HD + vd) * S_LEN + kt + ((vc_l ^ (vd & 7)) << 3)],
            &Vs[seg * 512]);
    }

    // ---- S^T = K·Q^T : 32 MFMAs; C row=key(quad*4+r), col=query(l15) ----
    float4v sc[2][4] = {};
#pragma unroll
    for (int nt = 0; nt < 4; ++nt) {
      const int krow = nt * 16 + l15;
#pragma unroll
      for (int c = 0; c < 4; ++c) {
        short8 kf = *(const short8*)((char*)Ks + krow * 256 + (((c * 4 + quad) ^ l15) << 4));
#pragma unroll
        for (int mt = 0; mt < 2; ++mt)
          sc[mt][nt] = __builtin_amdgcn_mfma_f32_16x16x32_bf16(kf, qf[mt][c], sc[mt][nt], 0, 0, 0);
      }
    }

    // ---- static-max softmax: p = exp2(s*SC - M0); sum in-lane + xor16/32 ----
#pragma unroll
    for (int mt = 0; mt < 2; ++mt) {
      float rs = 0.f;
#pragma unroll
      for (int nt = 0; nt < 4; ++nt)
#pragma unroll
        for (int r = 0; r < 4; ++r) {
          float p = exp2f(fmaf(sc[mt][nt][r], SC, -M0));
          sc[mt][nt][r] = p;
          rs += p;
        }
      rs += __shfl_xor(rs, 16, 64);
      rs += __shfl_xor(rs, 32, 64);
      l_[mt] += rs;
    }

    // ---- P^T -> per-wave LDS tile, sequential mt (write -> wait -> read) ----
    short8 pfr[2][2];
#pragma unroll
    for (int mt = 0; mt < 2; ++mt) {
#pragma unroll
      for (int nt = 0; nt < 4; ++nt) {
        uint2 w;
        w.x = pack_trunc(sc[mt][nt][0], sc[mt][nt][1]);
        w.y = pack_trunc(sc[mt][nt][2], sc[mt][nt][3]);
        const int chunk = (nt * 2 + (quad >> 1)) ^ (l15 & 7);
        *(uint2*)((char*)&Ps[wave][0] + l15 * 128 + chunk * 16 + (quad & 1) * 8) = w;
      }
      asm volatile("s_waitcnt lgkmcnt(0)" ::: "memory");  // writes visible
#pragma unroll
      for (int ko = 0; ko < 2; ++ko)
        pfr[mt][ko] = *(const short8*)((char*)&Ps[wave][0] + l15 * 128 +
                                       (((ko * 4 + quad) ^ (l15 & 7)) << 4));
      asm volatile("s_waitcnt lgkmcnt(0)" ::: "memory");  // reads done before overwrite
    }

    __syncthreads();   // B1: drains V(kt); all waves done reading Ks

    // ---- issue K(kt+64): overlapped with PV below ----
    if (kt + 64 < k_end) {
#pragma unroll
      for (int c = 0; c < 4; ++c) {
        const int seg = wave * 4 + c;
        const int kr = seg * 4 + kr_l;
        gld16(&rk[(size_t)(kt + 64 + kr) * DIM + h * HD + ((kc_l ^ (kr & 15)) << 3)],
              &Ks[seg * 512]);
      }
    }

    // ---- O^T += V^T · P^T : 32 MFMAs (vf shared across mt) ----
#pragma unroll
    for (int dt = 0; dt < 8; ++dt) {
      const int drow = dt * 16 + l15;
#pragma unroll
      for (int ko = 0; ko < 2; ++ko) {
        short8 vf = *(const short8*)((char*)Vs + drow * 128 + (((ko * 4 + quad) ^ (l15 & 7)) << 4));
#pragma unroll
        for (int mt = 0; mt < 2; ++mt)
          o[mt][dt] = __builtin_amdgcn_mfma_f32_16x16x32_bf16(vf, pfr[mt][ko], o[mt][dt], 0, 0, 0);
      }
    }

    __syncthreads();   // B2: drains K(kt+64); all waves done reading Vs
  }

  // ---- epilogue: unnormalized partial o (bf16, RNE) + l (f32) ----
#pragma unroll
  for (int mt = 0; mt < 2; ++mt) {
    const int q = q0 + mt * 16 + l15;
    const bool valid = q < S_LEN;
    const size_t rbase = ((size_t)(split * NH + h) * S_LEN + q) * HD;
#pragma unroll
    for (int dt = 0; dt < 8; ++dt) {
      if (valid) {
        ushort4 pk;
        pk.x = f2bf(o[mt][dt][0]); pk.y = f2bf(o[mt][dt][1]);
        pk.z = f2bf(o[mt][dt][2]); pk.w = f2bf(o[mt][dt][3]);
        *(ushort4*)&po[rbase + dt * 16 + quad * 4] = pk;
      }
    }
    if (quad == 0 && valid)
      pl[(size_t)(split * NH + h) * S_LEN + q] = l_[mt];
  }
}

// ---------------------------------------------------------------------------
// Merge 2 ksplit partials (shared static max -> plain sums).
// One wave per (h,q) row, 2 d-elems per lane.
// ---------------------------------------------------------------------------
__global__ void __launch_bounds__(256) attn_merge(
    const u16* __restrict__ po, const float* __restrict__ pl,
    u16* __restrict__ ao)
{
  const int gw = (blockIdx.x * 256 + threadIdx.x) >> 6;  // (h,q) row id
  const int lane = threadIdx.x & 63;
  const int h = gw / S_LEN;
  const int q = gw - h * S_LEN;
  const size_t r0 = (size_t)h * S_LEN + q;              // split 0 row
  const size_t r1 = (size_t)(NH + h) * S_LEN + q;       // split 1 row
  const float den = pl[r0] + pl[r1];
  const float inv = (den > 0.f) ? (1.0f / den) : 0.f;
  const ushort2 a = *(const ushort2*)&po[r0 * HD + lane * 2];
  const ushort2 b = *(const ushort2*)&po[r1 * HD + lane * 2];
  ushort2 out;
  out.x = f2bf((b2f(a.x) + b2f(b.x)) * inv);
  out.y = f2bf((b2f(a.y) + b2f(b.y)) * inv);
  *(ushort2*)&ao[(size_t)q * DIM + h * HD + lane * 2] = out;
}

// ---------------------------------------------------------------------------
extern "C" void kernel_launch(void* const* d_in, const int* in_sizes, int n_in,
                              void* d_out, int out_size, void* d_ws, size_t ws_size,
                              hipStream_t stream) {
  const float* x  = (const float*)d_in[0];
  const float* Wq = (const float*)d_in[1];
  const float* bq = (const float*)d_in[2];
  const float* Wk = (const float*)d_in[3];
  const float* bk = (const float*)d_in[4];
  const float* Wv = (const float*)d_in[5];
  const float* bv = (const float*)d_in[6];
  const float* Wo = (const float*)d_in[7];
  const float* bo = (const float*)d_in[8];
  const float* gq = (const float*)d_in[9];
  const float* gk = (const float*)d_in[10];
  const float* cf = (const float*)d_in[11];
  const float* sf = (const float*)d_in[12];
  const float* ch = (const float*)d_in[13];
  const float* sh = (const float*)d_in[14];
  const float* cw = (const float*)d_in[15];
  const float* sw = (const float*)d_in[16];

  char* ws = (char*)d_ws;
  const size_t sz  = (size_t)S_LEN * DIM * 2;  // 12.39 MB per bf16 activation
  const size_t wsz = (size_t)DIM * DIM * 2;    // 4.72 MB per bf16 weight
  u16* Xb  = (u16*)(ws);               // x bf16; reused as Vt after gemm_qkv
  u16* Qb  = (u16*)(ws + sz);          // becomes rq after rms_rope; reused as Ao
  u16* Kb  = (u16*)(ws + 2 * sz);      // becomes rk
  u16* Vb  = (u16*)(ws + 3 * sz);
  u16* Wqb = (u16*)(ws + 4 * sz);
  u16* Wkb = (u16*)(ws + 4 * sz + wsz);
  u16* Wvb = (u16*)(ws + 4 * sz + 2 * wsz);
  u16* Wob = (u16*)(ws + 4 * sz + 3 * wsz);
  // ksplit partials after the weights
  char* pbase = ws + 4 * sz + 4 * wsz;
  u16*   po = (u16*)pbase;                                    // 2*NH*S*HD bf16 = 24.8 MB
  float* pl = (float*)(pbase + (size_t)2 * NH * S_LEN * HD * 2);
  u16* Vt  = Xb;
  u16* Ao  = Qb;  // rq is dead after attn_kernel; merge writes here

  cast_all<<<(NX4 + 4 * NW4) / 256, 256, 0, stream>>>(
      x, Wq, Wk, Wv, Wo, Xb, Wqb, Wkb, Wvb, Wob);

  gemm_qkv<<<dim3(12, 32, 3), 256, 0, stream>>>(Xb, Wqb, Wkb, Wvb, bq, bk, bv, Qb, Kb, Vb);
  rms_rope<<<S_LEN, 256, 0, stream>>>(Qb, Kb, gq, gk, cf, sf, ch, sh, cw, sw);
  transpose_v<<<dim3(63, 24), 256, 0, stream>>>(Vb, Vt);
  attn_kernel<<<768, 256, 0, stream>>>(Qb, Kb, Vt, po, pl);
  attn_merge<<<(NH * S_LEN) / 4, 256, 0, stream>>>(po, pl, Ao);
  gemm_wo<<<dim3(12, 32), 256, 0, stream>>>(Ao, Wob, bo, (float*)d_out);
}